// Round 1
// baseline (599.071 us; speedup 1.0000x reference)
//
#include <hip/hip_runtime.h>

#define Bsz 512
#define Ssz 512
#define Isz 32
#define Hsz 128
#define BB  4            // 4 batch rows per block -> grid 128, half the CUs active
#define NT  512          // 8 waves
#define SI  (Ssz*Isz)    // 16384
#define XROW 16416       // shorts per staged-x row: 16384 + 32 pad (2-way banks, absorbs tail overread)
#define HROW 144         // shorts per h row: 288 B stride -> max 2-way bank aliasing (free)
#define LOG2E 1.44269504088896340736f

typedef __attribute__((ext_vector_type(8))) short bf16x8;
typedef __attribute__((ext_vector_type(4))) float f32x4;
typedef __attribute__((ext_vector_type(2))) unsigned int u32x2;

// single-instruction RNE f32->bf16 (low 16 bits of result); bit-identical to the add-round sequence
__device__ __forceinline__ unsigned cvtpk(float lo, float hi){
  unsigned r; asm("v_cvt_pk_bf16_f32 %0, %1, %2" : "=v"(r) : "v"(lo), "v"(hi));
  return r;
}
__device__ __forceinline__ unsigned short f2bf(float f){      // kept for one-time weight loads
  unsigned u = __float_as_uint(f);
  return (unsigned short)((u + 0x7FFFu + ((u >> 16) & 1u)) >> 16);
}
__device__ __forceinline__ float sigm_p(float xp){            // pre-scaled by log2e
  return __builtin_amdgcn_rcpf(1.f + __builtin_amdgcn_exp2f(-xp));
}
__device__ __forceinline__ float tanh_p(float xp2){           // pre-scaled by 2*log2e
  return 1.f - 2.f * __builtin_amdgcn_rcpf(1.f + __builtin_amdgcn_exp2f(xp2));
}
__device__ __forceinline__ bf16x8 ldw(const float* p, float s){
  bf16x8 r;
#pragma unroll
  for (int e=0;e<8;++e) r[e] = (short)f2bf(p[e]*s);
  return r;
}
__device__ __forceinline__ bf16x8 ldws(const float* pa, const float* pb, float s){
  bf16x8 r;
#pragma unroll
  for (int e=0;e<8;++e) r[e] = (short)f2bf((pa[e]+pb[e])*s);
  return r;
}

__global__ __launch_bounds__(NT, 2) void lstm_ae(
    const float* __restrict__ x,
    const float* __restrict__ eWih, const float* __restrict__ eWhh,
    const float* __restrict__ ebih, const float* __restrict__ ebhh,
    const float* __restrict__ dWih, const float* __restrict__ dWhh,
    const float* __restrict__ dbih, const float* __restrict__ dbhh,
    const float* __restrict__ fcW,  const float* __restrict__ fcb,
    float* __restrict__ out)
{
  __shared__ __attribute__((aligned(16))) unsigned short xl[BB*XROW];      // 131328 B
  __shared__ __attribute__((aligned(16))) unsigned short hbuf[2][BB][HROW];// 2304 B

  const int tid  = threadIdx.x;
  const int lane = tid & 63;
  const int wv   = tid >> 6;          // owns cols 16wv..16wv+15, all 4 gates
  const int c16  = lane & 15;
  const int quad = lane >> 4;
  const int hrow = c16 >> 2;          // batch row: A-rows 4r..4r+3 -> batch r; C row 4*quad -> batch quad
  const int col  = wv*16 + c16;
  const int bg0  = blockIdx.x * BB;

  // ---- stage x (4 batch rows) as bf16 into LDS (padded row stride) ----
#pragma unroll 2
  for (int i = tid*4; i < BB*SI; i += NT*4){
    f32x4 v = *(const f32x4*)(x + (size_t)bg0*SI + i);
    u32x2 r; r[0] = cvtpk(v[0], v[1]); r[1] = cvtpk(v[2], v[3]);
    *(u32x2*)(xl + (i>>14)*XROW + (i & (SI-1))) = r;
  }
  for (int i = tid; i < 2*BB*HROW; i += NT) ((unsigned short*)&hbuf[0][0][0])[i] = 0;

  // ---- encoder weights -> registers ----
  bf16x8 W[4][4], wx[4];
#pragma unroll
  for (int g=0;g<4;++g){
    int n = g*128 + col;
    float s = (g==2) ? 2.f*LOG2E : LOG2E;
#pragma unroll
    for (int m=0;m<4;++m) W[g][m] = ldw(eWhh + (size_t)n*Hsz + m*32 + quad*8, s);
    wx[g] = ldw(eWih + (size_t)n*Isz + quad*8, s);
  }
  float b_i = (ebih[0*Hsz+col]+ebhh[0*Hsz+col])*LOG2E;
  float b_f = (ebih[1*Hsz+col]+ebhh[1*Hsz+col])*LOG2E;
  float b_g = (ebih[2*Hsz+col]+ebhh[2*Hsz+col])*(2.f*LOG2E);
  float b_o = (ebih[3*Hsz+col]+ebhh[3*Hsz+col])*LOG2E;

  const f32x4 zero4 = {0.f,0.f,0.f,0.f};
  float cst = 0.f;                    // cell state: lane (quad,c16) owns batch row=quad, col

  const unsigned short* rd0 = &hbuf[0][hrow][0] + quad*8;
  const unsigned short* rd1 = &hbuf[1][hrow][0] + quad*8;
  unsigned short* wr0 = &hbuf[1][quad][col];
  unsigned short* wr1 = &hbuf[0][quad][col];

  // depth-2 accumulator merge + short serial tail (cvt_pk RNE, fma tanh-out)
  auto act = [&](const f32x4* aP, const f32x4* aQ, unsigned short* wp, bool upd){
    float pi = aP[0][0] + aQ[0][0] + b_i;
    float pf = aP[1][0] + aQ[1][0] + b_f;
    float pg = aP[2][0] + aQ[2][0] + b_g;
    float po = aP[3][0] + aQ[3][0] + b_o;
    float iv = sigm_p(pi), fv = sigm_p(pf), ov = sigm_p(po);
    float gv = tanh_p(pg);
    float cn = fv*cst + iv*gv;
    if (upd) cst = cn;
    float r  = __builtin_amdgcn_rcpf(1.f + __builtin_amdgcn_exp2f(cn*(2.f*LOG2E)));
    float hv = __builtin_fmaf(r, -2.f*ov, ov);      // ov*tanh(cn)
    *wp = (unsigned short)cvtpk(hv, hv);
  };

  auto ebody = [&](const unsigned short* rd, unsigned short* wp, bf16x8 axc,
                   const unsigned short* xp)->bf16x8{
    bf16x8 a0 = *(const bf16x8*)(rd);
    bf16x8 a1 = *(const bf16x8*)(rd+32);
    bf16x8 a2 = *(const bf16x8*)(rd+64);
    bf16x8 a3 = *(const bf16x8*)(rd+96);
    f32x4 aP[4], aQ[4];
    // x-contribution first: 4 independent MFMAs fill the ds_read latency window
#pragma unroll
    for (int g=0;g<4;++g) aQ[g] = __builtin_amdgcn_mfma_f32_16x16x32_bf16(axc, wx[g], zero4, 0,0,0);
#pragma unroll
    for (int g=0;g<4;++g) aP[g] = __builtin_amdgcn_mfma_f32_16x16x32_bf16(a0, W[g][0], zero4, 0,0,0);
#pragma unroll
    for (int g=0;g<4;++g) aP[g] = __builtin_amdgcn_mfma_f32_16x16x32_bf16(a1, W[g][1], aP[g], 0,0,0);
#pragma unroll
    for (int g=0;g<4;++g) aQ[g] = __builtin_amdgcn_mfma_f32_16x16x32_bf16(a2, W[g][2], aQ[g], 0,0,0);
#pragma unroll
    for (int g=0;g<4;++g) aQ[g] = __builtin_amdgcn_mfma_f32_16x16x32_bf16(a3, W[g][3], aQ[g], 0,0,0);
    act(aP, aQ, wp, true);
    bf16x8 axn = *(const bf16x8*)(xp);     // prefetch next step's x fragment (read-only region)
    __syncthreads();
    return axn;
  };

  __syncthreads();   // x staged, hbuf zeroed

  // ---------------- encoder (512 steps, unrolled x2) ----------------
  const unsigned short* xq = xl + hrow*XROW + quad*8;
  bf16x8 axc = *(const bf16x8*)(xq);
  const unsigned short* xp = xq + 32;
  for (int it=0; it<Ssz/2; ++it){
    axc = ebody(rd0, wr0, axc, xp); xp += 32;
    axc = ebody(rd1, wr1, axc, xp); xp += 32;
  }

  // ---------------- decoder ----------------
  b_i = (dbih[0*Hsz+col]+dbhh[0*Hsz+col])*LOG2E;
  b_f = (dbih[1*Hsz+col]+dbhh[1*Hsz+col])*LOG2E;
  b_g = (dbih[2*Hsz+col]+dbhh[2*Hsz+col])*(2.f*LOG2E);
  b_o = (dbih[3*Hsz+col]+dbhh[3*Hsz+col])*LOG2E;

  // step 0: gates = enc_h @ dWhh^T + b (cell stays enc_c; enc_h in hbuf[0])
#pragma unroll
  for (int g=0;g<4;++g){
    int n = g*128 + col;
    float s = (g==2) ? 2.f*LOG2E : LOG2E;
#pragma unroll
    for (int m=0;m<4;++m) W[g][m] = ldw(dWhh + (size_t)n*Hsz + m*32 + quad*8, s);
  }
  {
    bf16x8 a0 = *(const bf16x8*)(rd0);
    bf16x8 a1 = *(const bf16x8*)(rd0+32);
    bf16x8 a2 = *(const bf16x8*)(rd0+64);
    bf16x8 a3 = *(const bf16x8*)(rd0+96);
    f32x4 aP[4], aQ[4];
#pragma unroll
    for (int g=0;g<4;++g) aP[g] = __builtin_amdgcn_mfma_f32_16x16x32_bf16(a0, W[g][0], zero4, 0,0,0);
#pragma unroll
    for (int g=0;g<4;++g) aP[g] = __builtin_amdgcn_mfma_f32_16x16x32_bf16(a1, W[g][1], aP[g], 0,0,0);
#pragma unroll
    for (int g=0;g<4;++g) aQ[g] = __builtin_amdgcn_mfma_f32_16x16x32_bf16(a2, W[g][2], zero4, 0,0,0);
#pragma unroll
    for (int g=0;g<4;++g) aQ[g] = __builtin_amdgcn_mfma_f32_16x16x32_bf16(a3, W[g][3], aQ[g], 0,0,0);
    act(aP, aQ, wr0, false);
    __syncthreads();
  }

  // steps >=1: W = (dWih + dWhh); fc on waves 6,7; frames streamed to global
#pragma unroll
  for (int g=0;g<4;++g){
    int n = g*128 + col;
    float s = (g==2) ? 2.f*LOG2E : LOG2E;
#pragma unroll
    for (int m=0;m<4;++m){
      const float* pa = dWih + (size_t)n*Hsz + m*32 + quad*8;
      const float* pb = dWhh + (size_t)n*Hsz + m*32 + quad*8;
      W[g][m] = ldws(pa, pb, s);
    }
  }
  bf16x8 wf[4];
  f32x4 biasf4 = {0.f,0.f,0.f,0.f};
  const int nf = (wv >= 6) ? (wv-6)*16 + c16 : 0;
  if (wv >= 6){
#pragma unroll
    for (int m=0;m<4;++m) wf[m] = ldw(fcW + (size_t)nf*Hsz + m*32 + quad*8, 1.f);
    float bfc = fcb[nf];
    biasf4[0]=bfc; biasf4[1]=bfc; biasf4[2]=bfc; biasf4[3]=bfc;
  }
  float* fp = out + (size_t)(bg0 + quad)*SI + nf;   // frame slot, +32 floats/step (wv>=6 only)

  auto dbody = [&](const unsigned short* rd, unsigned short* wp, float* fpp){
    bf16x8 a0 = *(const bf16x8*)(rd);
    bf16x8 a1 = *(const bf16x8*)(rd+32);
    bf16x8 a2 = *(const bf16x8*)(rd+64);
    bf16x8 a3 = *(const bf16x8*)(rd+96);
    f32x4 aP[4], aQ[4];
#pragma unroll
    for (int g=0;g<4;++g) aP[g] = __builtin_amdgcn_mfma_f32_16x16x32_bf16(a0, W[g][0], zero4, 0,0,0);
#pragma unroll
    for (int g=0;g<4;++g) aP[g] = __builtin_amdgcn_mfma_f32_16x16x32_bf16(a1, W[g][1], aP[g], 0,0,0);
#pragma unroll
    for (int g=0;g<4;++g) aQ[g] = __builtin_amdgcn_mfma_f32_16x16x32_bf16(a2, W[g][2], zero4, 0,0,0);
#pragma unroll
    for (int g=0;g<4;++g) aQ[g] = __builtin_amdgcn_mfma_f32_16x16x32_bf16(a3, W[g][3], aQ[g], 0,0,0);
    if (wv >= 6){
      f32x4 fa = __builtin_amdgcn_mfma_f32_16x16x32_bf16(a0, wf[0], biasf4, 0,0,0);
      fa = __builtin_amdgcn_mfma_f32_16x16x32_bf16(a1, wf[1], fa, 0,0,0);
      fa = __builtin_amdgcn_mfma_f32_16x16x32_bf16(a2, wf[2], fa, 0,0,0);
      fa = __builtin_amdgcn_mfma_f32_16x16x32_bf16(a3, wf[3], fa, 0,0,0);
      act(aP, aQ, wp, false);
      *fpp = fa[0];                    // fire-and-forget global store, off critical path
    } else {
      act(aP, aQ, wp, false);
    }
    __syncthreads();
  };

  // t = 1..510 (255 pairs), then t = 511 (stores frames 0..510)
  for (int it=0; it<255; ++it){
    dbody(rd1, wr1, fp); fp += 32;
    dbody(rd0, wr0, fp); fp += 32;
  }
  dbody(rd1, wr1, fp); fp += 32;

  // epilogue: frame 511 from h(511) (in hbuf[0])
  if (wv >= 6){
    bf16x8 a0 = *(const bf16x8*)(rd0);
    bf16x8 a1 = *(const bf16x8*)(rd0+32);
    bf16x8 a2 = *(const bf16x8*)(rd0+64);
    bf16x8 a3 = *(const bf16x8*)(rd0+96);
    f32x4 fa = __builtin_amdgcn_mfma_f32_16x16x32_bf16(a0, wf[0], biasf4, 0,0,0);
    fa = __builtin_amdgcn_mfma_f32_16x16x32_bf16(a1, wf[1], fa, 0,0,0);
    fa = __builtin_amdgcn_mfma_f32_16x16x32_bf16(a2, wf[2], fa, 0,0,0);
    fa = __builtin_amdgcn_mfma_f32_16x16x32_bf16(a3, wf[3], fa, 0,0,0);
    *fp = fa[0];
  }
}

extern "C" void kernel_launch(void* const* d_in, const int* in_sizes, int n_in,
                              void* d_out, int out_size, void* d_ws, size_t ws_size,
                              hipStream_t stream) {
  const float* x    = (const float*)d_in[0];
  const float* eWih = (const float*)d_in[1];
  const float* eWhh = (const float*)d_in[2];
  const float* ebih = (const float*)d_in[3];
  const float* ebhh = (const float*)d_in[4];
  const float* dWih = (const float*)d_in[5];
  const float* dWhh = (const float*)d_in[6];
  const float* dbih = (const float*)d_in[7];
  const float* dbhh = (const float*)d_in[8];
  const float* fcW  = (const float*)d_in[9];
  const float* fcb  = (const float*)d_in[10];
  float* outp = (float*)d_out;
  (void)d_ws; (void)ws_size; (void)in_sizes; (void)n_in; (void)out_size;
  lstm_ae<<<dim3(Bsz/BB), dim3(NT), 0, stream>>>(
      x, eWih, eWhh, ebih, ebhh, dWih, dWhh, dbih, dbhh, fcW, fcb, outp);
}